// Round 6
// baseline (521.213 us; speedup 1.0000x reference)
//
#include <hip/hip_runtime.h>

// JTMPN message-passing network, MI355X — MFMA bf16, round 6.
//
// ws layout (u16 units), total 107.84 MB:
//   tree    [NMESS*256]        bf16 tree messages
//   gmA     [NBND*256]         graph_message ping   (f32 'hidden' aliases here later)
//   gmB     [NBND*256]         graph_message pong
//   wfrag_h [10*16*64*8]       W_h|W_i frag-native bf16 (160 KB, L2-hot)
//   wfrag_o [10*16*64*8]       W_o frag-native (160 KB)
//
// k_main<MODE>: 64-row x 256-col tile, 4 waves, wave-tile 64x64, MFMA 16x16x32.
//   MODE 0 (gm0):  relu(fbonds@W_i^T)                          -> bf16
//   MODE 1 (mp):   relu(nei_sum@W_h^T + fbonds@W_i^T)          -> bf16
//   MODE 2 (atom): relu(nei_sum@W_o'^T + fatoms@W_o''^T + b_o) -> f32
// Gather indices go through the SCALAR path (uniform bond row -> s_load of
// graph[], scalar pointer select, saddr-form vector loads). LDS = a1 only
// (32768 B exactly) -> 5 blocks/CU.

#define H     256
#define NBND  100000
#define NATM  50000
#define NMESS 10000
#define MAXNB 10
#define AF    35
#define BF    40
#define NPAIR 10000
#define NMOL  2000
#define APM   25

typedef unsigned short u16;
typedef unsigned int   u32;
using short8 = __attribute__((ext_vector_type(8))) short;
using f32x4  = __attribute__((ext_vector_type(4))) float;

__device__ __forceinline__ float bflo(u32 w) { return __uint_as_float(w << 16); }
__device__ __forceinline__ float bfhi(u32 w) { return __uint_as_float(w & 0xffff0000u); }
__device__ __forceinline__ u16 f2bf(float f) {
    u32 x = __float_as_uint(f);
    return (u16)((x + 0x7fffu + ((x >> 16) & 1u)) >> 16);   // RNE
}
__device__ __forceinline__ u32 pack2(float a, float b) {
    return (u32)f2bf(a) | ((u32)f2bf(b) << 16);
}

// tree_message f32 -> bf16
__global__ __launch_bounds__(256) void k_treecvt(const float* __restrict__ tree_in,
                                                 u16* __restrict__ tree) {
    const long i = ((long)blockIdx.x * 256 + threadIdx.x) * 4;
    float4 v = *(const float4*)(tree_in + i);
    uint2 o;
    o.x = pack2(v.x, v.y);
    o.y = pack2(v.z, v.w);
    *(uint2*)(tree + i) = o;
}

// Pack B = [Wm[:, offm:offm+256] | We[:, 0:nce] | 0-pad] (320 x 256, B[k][n]) into
// frag-native: dst[((ks*16+nt)*64+lane)*8+e] = bf16(B[ks*32+(lane>>4)*8+e][nt*16+(lane&15)])
__global__ __launch_bounds__(64) void k_wfrag(const float* __restrict__ Wm, int ldm, int offm,
                                              const float* __restrict__ We, int lde, int nce,
                                              u16* __restrict__ dst) {
    const int t = threadIdx.x;
    const int ks = blockIdx.x >> 4, nt = blockIdx.x & 15;
    const int n = nt * 16 + (t & 15);
    u16 vals[8];
#pragma unroll
    for (int e = 0; e < 8; ++e) {
        const int k = ks * 32 + (t >> 4) * 8 + e;
        float v;
        if (k < 256)            v = Wm[(long)n * ldm + offm + k];
        else if (k - 256 < nce) v = We[(long)n * lde + (k - 256)];
        else                    v = 0.f;
        vals[e] = f2bf(v);
    }
    *(uint4*)(dst + ((size_t)blockIdx.x * 64 + t) * 8) = *(const uint4*)vals;
}

// ext features -> A-frag directly from global (ks = 8 or 9).
template <int MODE>
__device__ __forceinline__ short8 ldext_frag(const float* __restrict__ ext,
                                             int rr, int lane, int ks, int NR) {
    constexpr int EXT = (MODE == 2) ? AF : BF;
    const int c0 = (ks == 9 ? 32 : 0) + ((lane >> 4) * 8);
    union { short8 s; u32 u[4]; u16 h[8]; } cv;
    cv.u[0] = cv.u[1] = cv.u[2] = cv.u[3] = 0;
    if (rr >= NR || c0 >= EXT) return cv.s;
    const float* p = ext + (size_t)rr * EXT + c0;
    if (MODE != 2) {   // BF=40: rows 160B, c0 in {0,8,16,24,32} all valid
        float4 v0 = *(const float4*)p;
        float4 v1 = *(const float4*)(p + 4);
        cv.u[0] = pack2(v0.x, v0.y);
        cv.u[1] = pack2(v0.z, v0.w);
        cv.u[2] = pack2(v1.x, v1.y);
        cv.u[3] = pack2(v1.z, v1.w);
    } else {           // AF=35: unaligned rows, partial tail
#pragma unroll
        for (int e = 0; e < 8; ++e)
            cv.h[e] = (c0 + e < EXT) ? f2bf(p[e]) : (u16)0;
    }
    return cv.s;
}

template <int MODE>   // 0: gm0, 1: mp, 2: atom
__global__ __launch_bounds__(256, 5) void k_main(
        const int* __restrict__ graph, const u16* __restrict__ tree,
        const u16* __restrict__ gm_in, const float* __restrict__ ext,
        const u16* __restrict__ wfrag, const float* __restrict__ b_o,
        u16* __restrict__ out_bf, float* __restrict__ out_f) {
    constexpr int NR = (MODE == 2) ? NATM : NBND;
    __shared__ __align__(16) u16 a1[64 * 256];   // 32768 B exactly -> 5 blocks/CU

    const int t = threadIdx.x;
    const int lane = t & 63;
    const int w = t >> 6;
    const int r0 = blockIdx.x * 64;

    if (MODE != 0) {
        // gather: wave w owns rows w*16..+15; lane covers dims [4*lane, 4*lane+4).
        // Bond index fetch is SCALAR: b uniform -> s_load graph row, scalar
        // pointer select, saddr vector loads of the 512B message row.
        for (int bb = 0; bb < 16; ++bb) {
            const int b = __builtin_amdgcn_readfirstlane(r0 + w * 16 + bb);
            float s0 = 0.f, s1 = 0.f, s2 = 0.f, s3 = 0.f;
            if (b < NR) {
                const int* gp = graph + (size_t)b * MAXNB;   // uniform address
#pragma unroll
                for (int j = 0; j < MAXNB; ++j) {
                    const int idx = __builtin_amdgcn_readfirstlane(gp[j]);
                    const u16* p = (idx < NMESS) ? tree + (size_t)idx * H
                                                 : gm_in + (size_t)(idx - NMESS) * H;
                    const uint2 q = *(const uint2*)(p + lane * 4);
                    s0 += bflo(q.x); s1 += bfhi(q.x);
                    s2 += bflo(q.y); s3 += bfhi(q.y);
                }
            }
            uint2 o;
            o.x = pack2(s0, s1);
            o.y = pack2(s2, s3);
            const int bnd = w * 16 + bb;
            const int bo = (bnd * 512 + lane * 8) ^ ((bnd & 7) << 4);
            *(uint2*)((char*)a1 + bo) = o;
        }
        __syncthreads();
    }

    // ---- MFMA k-loop (no barriers): A from LDS/global, B streams from L2 ----
    f32x4 acc[4][4];
#pragma unroll
    for (int mt = 0; mt < 4; ++mt)
#pragma unroll
        for (int nt = 0; nt < 4; ++nt) acc[mt][nt] = (f32x4){0.f, 0.f, 0.f, 0.f};

    const short8* wf = (const short8*)wfrag;
    constexpr int KS0 = (MODE == 0) ? 8 : 0;
#pragma unroll
    for (int ks = KS0; ks < 10; ++ks) {
        short8 a[4], bf[4];
#pragma unroll
        for (int mt = 0; mt < 4; ++mt) {
            const int row = mt * 16 + (lane & 15);
            if (ks < 8) {
                const int bo = (row * 512 + (ks * 32 + (lane >> 4) * 8) * 2) ^ ((row & 7) << 4);
                a[mt] = *(const short8*)((const char*)a1 + bo);
            } else {
                a[mt] = ldext_frag<MODE>(ext, r0 + row, lane, ks, NR);
            }
        }
#pragma unroll
        for (int nt = 0; nt < 4; ++nt)
            bf[nt] = wf[((size_t)(ks * 16 + (w * 4 + nt)) * 64) + lane];
#pragma unroll
        for (int mt = 0; mt < 4; ++mt)
#pragma unroll
            for (int nt = 0; nt < 4; ++nt)
                acc[mt][nt] = __builtin_amdgcn_mfma_f32_16x16x32_bf16(a[mt], bf[nt], acc[mt][nt], 0, 0, 0);
    }

    // ---- epilogue: D frag mapping col=lane&15, row=(lane>>4)*4+reg ----
    float bo4[4];
    if (MODE == 2) {
#pragma unroll
        for (int nt = 0; nt < 4; ++nt) bo4[nt] = b_o[w * 64 + nt * 16 + (lane & 15)];
    }
#pragma unroll
    for (int mt = 0; mt < 4; ++mt) {
#pragma unroll
        for (int nt = 0; nt < 4; ++nt) {
            const int col = w * 64 + nt * 16 + (lane & 15);
#pragma unroll
            for (int r = 0; r < 4; ++r) {
                const int row = r0 + mt * 16 + (lane >> 4) * 4 + r;
                if (row < NR) {
                    const float v = acc[mt][nt][r];
                    if (MODE == 2)
                        out_f[(size_t)row * H + col] = fmaxf(v + bo4[nt], 0.f);
                    else
                        out_bf[(size_t)row * H + col] = f2bf(fmaxf(v, 0.f));
                }
            }
        }
    }
}

// collated[p] = 0.5*(gm3[i0] + gm3[i1]) -> f32 out
__global__ __launch_bounds__(256) void k_collated(const int* __restrict__ pair_idx,
                                                  const u16* __restrict__ gm,
                                                  float* __restrict__ out) {
    const int w = threadIdx.x >> 6, lane = threadIdx.x & 63;
    const long p = (long)blockIdx.x * 4 + w;
    if (p >= NPAIR) return;
    const size_t i0 = (size_t)pair_idx[p * 2 + 0];
    const size_t i1 = (size_t)pair_idx[p * 2 + 1];
    uint2 qa = *(const uint2*)(gm + i0 * H + lane * 4);
    uint2 qb = *(const uint2*)(gm + i1 * H + lane * 4);
    float4 o;
    o.x = 0.5f * (bflo(qa.x) + bflo(qb.x));
    o.y = 0.5f * (bfhi(qa.x) + bfhi(qb.x));
    o.z = 0.5f * (bflo(qa.y) + bflo(qb.y));
    o.w = 0.5f * (bfhi(qa.y) + bfhi(qb.y));
    *(float4*)(out + p * H + lane * 4) = o;
}

// mol_vecs[m] = mean over 25 atoms of hidden -> f32 out
__global__ __launch_bounds__(256) void k_molmean(const float* __restrict__ hidden,
                                                 float* __restrict__ out) {
    const int m = blockIdx.x, c = threadIdx.x;
    float s = 0.f;
#pragma unroll
    for (int a = 0; a < APM; ++a)
        s += hidden[((long)m * APM + a) * H + c];
    out[(long)m * H + c] = s * (1.f / APM);
}

extern "C" void kernel_launch(void* const* d_in, const int* in_sizes, int n_in,
                              void* d_out, int out_size, void* d_ws, size_t ws_size,
                              hipStream_t stream) {
    (void)in_sizes; (void)n_in; (void)out_size;
    const float* fatoms  = (const float*)d_in[0];
    const float* fbonds  = (const float*)d_in[1];
    const float* tree_in = (const float*)d_in[2];
    const int* agraph    = (const int*)d_in[3];
    const int* bgraph    = (const int*)d_in[4];
    const int* pair_idx  = (const int*)d_in[5];
    const float* W_i = (const float*)d_in[6];
    const float* W_h = (const float*)d_in[7];
    const float* W_o = (const float*)d_in[8];
    const float* b_o = (const float*)d_in[9];

    float* out = (float*)d_out;   // [mol_vecs 2000*256 | collated 10000*256], f32

    const size_t WFRAG = 10 * 16 * 64 * 8;   // u16 elems per frag table
    const size_t need = ((size_t)NMESS + 2 * (size_t)NBND) * H * sizeof(u16)
                        + 2 * WFRAG * sizeof(u16);
    if (ws_size < need) return;   // diagnostic guard

    u16* tree    = (u16*)d_ws;
    u16* gmA     = tree + (size_t)NMESS * H;
    u16* gmB     = gmA + (size_t)NBND * H;
    u16* wfrag_h = gmB + (size_t)NBND * H;
    u16* wfrag_o = wfrag_h + WFRAG;
    float* hidden = (float*)gmA;   // gmA dead after mp#3

    const int GB = (NBND + 63) / 64;   // 1563
    const int GA = (NATM + 63) / 64;   // 782

    k_treecvt<<<(NMESS * H) / 1024, 256, 0, stream>>>(tree_in, tree);
    k_wfrag<<<160, 64, 0, stream>>>(W_h, 256, 0, W_i, BF, BF, wfrag_h);
    k_wfrag<<<160, 64, 0, stream>>>(W_o, 291, AF, W_o, 291, AF, wfrag_o);

    k_main<0><<<GB, 256, 0, stream>>>(nullptr, tree, gmA, fbonds, wfrag_h, nullptr, gmA, nullptr);
    k_main<1><<<GB, 256, 0, stream>>>(bgraph, tree, gmA, fbonds, wfrag_h, nullptr, gmB, nullptr);
    k_main<1><<<GB, 256, 0, stream>>>(bgraph, tree, gmB, fbonds, wfrag_h, nullptr, gmA, nullptr);
    k_main<1><<<GB, 256, 0, stream>>>(bgraph, tree, gmA, fbonds, wfrag_h, nullptr, gmB, nullptr);
    k_collated<<<NPAIR / 4, 256, 0, stream>>>(pair_idx, gmB, out + (size_t)NMOL * H);
    k_main<2><<<GA, 256, 0, stream>>>(agraph, tree, gmB, fatoms, wfrag_o, b_o, nullptr, hidden);
    k_molmean<<<NMOL, 256, 0, stream>>>(hidden, out);
}

// Round 7
// 362.017 us; speedup vs baseline: 1.4397x; 1.4397x over previous
//
#include <hip/hip_runtime.h>

// JTMPN message-passing network, MI355X — MFMA bf16, round 7.
// (= round 5 structure + 2-deep software-pipelined gather; r6 scalar path reverted)
//
// ws layout (u16 units), total 107.84 MB:
//   tree    [NMESS*256]        bf16 tree messages
//   gmA     [NBND*256]         graph_message ping   (f32 'hidden' aliases here later)
//   gmB     [NBND*256]         graph_message pong
//   wfrag_h [10*16*64*8]       W_h|W_i frag-native bf16 (160 KB, L2-hot)
//   wfrag_o [10*16*64*8]       W_o frag-native (160 KB)
//
// k_main<MODE>: 64-row x 256-col tile, 4 waves, wave-tile 64x64, MFMA 16x16x32.
//   MODE 0 (gm0):  relu(fbonds@W_i^T)                          -> bf16
//   MODE 1 (mp):   relu(nei_sum@W_h^T + fbonds@W_i^T)          -> bf16
//   MODE 2 (atom): relu(nei_sum@W_o'^T + fatoms@W_o''^T + b_o) -> f32
// Gather: idx staged in LDS (coalesced), readfirstlane -> SGPR base, and the
// per-wave loop processes 2 bond rows per iteration with all 20 dwordx2 loads
// issued before accumulation (double MLP vs r5).

#define H     256
#define NBND  100000
#define NATM  50000
#define NMESS 10000
#define MAXNB 10
#define AF    35
#define BF    40
#define NPAIR 10000
#define NMOL  2000
#define APM   25

typedef unsigned short u16;
typedef unsigned int   u32;
using short8 = __attribute__((ext_vector_type(8))) short;
using f32x4  = __attribute__((ext_vector_type(4))) float;

__device__ __forceinline__ float bflo(u32 w) { return __uint_as_float(w << 16); }
__device__ __forceinline__ float bfhi(u32 w) { return __uint_as_float(w & 0xffff0000u); }
__device__ __forceinline__ u16 f2bf(float f) {
    u32 x = __float_as_uint(f);
    return (u16)((x + 0x7fffu + ((x >> 16) & 1u)) >> 16);   // RNE
}
__device__ __forceinline__ u32 pack2(float a, float b) {
    return (u32)f2bf(a) | ((u32)f2bf(b) << 16);
}

// tree_message f32 -> bf16
__global__ __launch_bounds__(256) void k_treecvt(const float* __restrict__ tree_in,
                                                 u16* __restrict__ tree) {
    const long i = ((long)blockIdx.x * 256 + threadIdx.x) * 4;
    float4 v = *(const float4*)(tree_in + i);
    uint2 o;
    o.x = pack2(v.x, v.y);
    o.y = pack2(v.z, v.w);
    *(uint2*)(tree + i) = o;
}

// Pack B = [Wm[:, offm:offm+256] | We[:, 0:nce] | 0-pad] (320 x 256, B[k][n]) into
// frag-native: dst[((ks*16+nt)*64+lane)*8+e] = bf16(B[ks*32+(lane>>4)*8+e][nt*16+(lane&15)])
__global__ __launch_bounds__(64) void k_wfrag(const float* __restrict__ Wm, int ldm, int offm,
                                              const float* __restrict__ We, int lde, int nce,
                                              u16* __restrict__ dst) {
    const int t = threadIdx.x;
    const int ks = blockIdx.x >> 4, nt = blockIdx.x & 15;
    const int n = nt * 16 + (t & 15);
    u16 vals[8];
#pragma unroll
    for (int e = 0; e < 8; ++e) {
        const int k = ks * 32 + (t >> 4) * 8 + e;
        float v;
        if (k < 256)            v = Wm[(long)n * ldm + offm + k];
        else if (k - 256 < nce) v = We[(long)n * lde + (k - 256)];
        else                    v = 0.f;
        vals[e] = f2bf(v);
    }
    *(uint4*)(dst + ((size_t)blockIdx.x * 64 + t) * 8) = *(const uint4*)vals;
}

// ext features -> A-frag directly from global (ks = 8 or 9).
template <int MODE>
__device__ __forceinline__ short8 ldext_frag(const float* __restrict__ ext,
                                             int rr, int lane, int ks, int NR) {
    constexpr int EXT = (MODE == 2) ? AF : BF;
    const int c0 = (ks == 9 ? 32 : 0) + ((lane >> 4) * 8);
    union { short8 s; u32 u[4]; u16 h[8]; } cv;
    cv.u[0] = cv.u[1] = cv.u[2] = cv.u[3] = 0;
    if (rr >= NR || c0 >= EXT) return cv.s;
    const float* p = ext + (size_t)rr * EXT + c0;
    if (MODE != 2) {   // BF=40: rows 160B, c0 in {0,8,16,24,32} all valid
        float4 v0 = *(const float4*)p;
        float4 v1 = *(const float4*)(p + 4);
        cv.u[0] = pack2(v0.x, v0.y);
        cv.u[1] = pack2(v0.z, v0.w);
        cv.u[2] = pack2(v1.x, v1.y);
        cv.u[3] = pack2(v1.z, v1.w);
    } else {           // AF=35: unaligned rows, partial tail
#pragma unroll
        for (int e = 0; e < 8; ++e)
            cv.h[e] = (c0 + e < EXT) ? f2bf(p[e]) : (u16)0;
    }
    return cv.s;
}

template <int MODE>   // 0: gm0, 1: mp, 2: atom
__global__ __launch_bounds__(256, 4) void k_main(
        const int* __restrict__ graph, const u16* __restrict__ tree,
        const u16* __restrict__ gm_in, const float* __restrict__ ext,
        const u16* __restrict__ wfrag, const float* __restrict__ b_o,
        u16* __restrict__ out_bf, float* __restrict__ out_f) {
    constexpr int NR = (MODE == 2) ? NATM : NBND;
    __shared__ __align__(16) u16 a1[64 * 256];   // gathered nei sums, XOR-swizzled (32 KB)
    __shared__ int idx_lds[64 * MAXNB];

    const int t = threadIdx.x;
    const int lane = t & 63;
    const int w = t >> 6;
    const int r0 = blockIdx.x * 64;

    if (MODE != 0) {
        for (int i = t; i < 64 * MAXNB; i += 256) {
            const int r = r0 + i / MAXNB;
            idx_lds[i] = (r < NR) ? graph[(long)r * MAXNB + i % MAXNB] : 0;   // 0 -> zero tree row
        }
        __syncthreads();
        // gather: wave w owns rows w*16..+15, 2 rows per iteration (20 loads in flight);
        // lane covers dims [4*lane, 4*lane+4)
        for (int bb = 0; bb < 16; bb += 2) {
            const int b0 = w * 16 + bb, b1 = b0 + 1;
            const u16* p0[MAXNB];
            const u16* p1[MAXNB];
#pragma unroll
            for (int j = 0; j < MAXNB; ++j) {
                const int i0 = __builtin_amdgcn_readfirstlane(idx_lds[b0 * MAXNB + j]);
                const int i1 = __builtin_amdgcn_readfirstlane(idx_lds[b1 * MAXNB + j]);
                p0[j] = (i0 < NMESS) ? tree + (size_t)i0 * H : gm_in + (size_t)(i0 - NMESS) * H;
                p1[j] = (i1 < NMESS) ? tree + (size_t)i1 * H : gm_in + (size_t)(i1 - NMESS) * H;
            }
            uint2 q0[MAXNB], q1[MAXNB];
#pragma unroll
            for (int j = 0; j < MAXNB; ++j) q0[j] = *(const uint2*)(p0[j] + lane * 4);
#pragma unroll
            for (int j = 0; j < MAXNB; ++j) q1[j] = *(const uint2*)(p1[j] + lane * 4);
            float s0 = 0.f, s1 = 0.f, s2 = 0.f, s3 = 0.f;
            float u0 = 0.f, u1 = 0.f, u2 = 0.f, u3 = 0.f;
#pragma unroll
            for (int j = 0; j < MAXNB; ++j) {
                s0 += bflo(q0[j].x); s1 += bfhi(q0[j].x);
                s2 += bflo(q0[j].y); s3 += bfhi(q0[j].y);
                u0 += bflo(q1[j].x); u1 += bfhi(q1[j].x);
                u2 += bflo(q1[j].y); u3 += bfhi(q1[j].y);
            }
            uint2 o0, o1;
            o0.x = pack2(s0, s1); o0.y = pack2(s2, s3);
            o1.x = pack2(u0, u1); o1.y = pack2(u2, u3);
            const int bo0 = (b0 * 512 + lane * 8) ^ ((b0 & 7) << 4);
            const int bo1 = (b1 * 512 + lane * 8) ^ ((b1 & 7) << 4);
            *(uint2*)((char*)a1 + bo0) = o0;
            *(uint2*)((char*)a1 + bo1) = o1;
        }
        __syncthreads();
    }

    // ---- MFMA k-loop (no barriers): A from LDS/global, B streams from L2 ----
    f32x4 acc[4][4];
#pragma unroll
    for (int mt = 0; mt < 4; ++mt)
#pragma unroll
        for (int nt = 0; nt < 4; ++nt) acc[mt][nt] = (f32x4){0.f, 0.f, 0.f, 0.f};

    const short8* wf = (const short8*)wfrag;
    constexpr int KS0 = (MODE == 0) ? 8 : 0;
#pragma unroll
    for (int ks = KS0; ks < 10; ++ks) {
        short8 a[4], bf[4];
#pragma unroll
        for (int mt = 0; mt < 4; ++mt) {
            const int row = mt * 16 + (lane & 15);
            if (ks < 8) {
                const int bo = (row * 512 + (ks * 32 + (lane >> 4) * 8) * 2) ^ ((row & 7) << 4);
                a[mt] = *(const short8*)((const char*)a1 + bo);
            } else {
                a[mt] = ldext_frag<MODE>(ext, r0 + row, lane, ks, NR);
            }
        }
#pragma unroll
        for (int nt = 0; nt < 4; ++nt)
            bf[nt] = wf[((size_t)(ks * 16 + (w * 4 + nt)) * 64) + lane];
#pragma unroll
        for (int mt = 0; mt < 4; ++mt)
#pragma unroll
            for (int nt = 0; nt < 4; ++nt)
                acc[mt][nt] = __builtin_amdgcn_mfma_f32_16x16x32_bf16(a[mt], bf[nt], acc[mt][nt], 0, 0, 0);
    }

    // ---- epilogue: D frag mapping col=lane&15, row=(lane>>4)*4+reg ----
    float bo4[4];
    if (MODE == 2) {
#pragma unroll
        for (int nt = 0; nt < 4; ++nt) bo4[nt] = b_o[w * 64 + nt * 16 + (lane & 15)];
    }
#pragma unroll
    for (int mt = 0; mt < 4; ++mt) {
#pragma unroll
        for (int nt = 0; nt < 4; ++nt) {
            const int col = w * 64 + nt * 16 + (lane & 15);
#pragma unroll
            for (int r = 0; r < 4; ++r) {
                const int row = r0 + mt * 16 + (lane >> 4) * 4 + r;
                if (row < NR) {
                    const float v = acc[mt][nt][r];
                    if (MODE == 2)
                        out_f[(size_t)row * H + col] = fmaxf(v + bo4[nt], 0.f);
                    else
                        out_bf[(size_t)row * H + col] = f2bf(fmaxf(v, 0.f));
                }
            }
        }
    }
}

// collated[p] = 0.5*(gm3[i0] + gm3[i1]) -> f32 out
__global__ __launch_bounds__(256) void k_collated(const int* __restrict__ pair_idx,
                                                  const u16* __restrict__ gm,
                                                  float* __restrict__ out) {
    const int w = threadIdx.x >> 6, lane = threadIdx.x & 63;
    const long p = (long)blockIdx.x * 4 + w;
    if (p >= NPAIR) return;
    const size_t i0 = (size_t)pair_idx[p * 2 + 0];
    const size_t i1 = (size_t)pair_idx[p * 2 + 1];
    uint2 qa = *(const uint2*)(gm + i0 * H + lane * 4);
    uint2 qb = *(const uint2*)(gm + i1 * H + lane * 4);
    float4 o;
    o.x = 0.5f * (bflo(qa.x) + bflo(qb.x));
    o.y = 0.5f * (bfhi(qa.x) + bfhi(qb.x));
    o.z = 0.5f * (bflo(qa.y) + bflo(qb.y));
    o.w = 0.5f * (bfhi(qa.y) + bfhi(qb.y));
    *(float4*)(out + p * H + lane * 4) = o;
}

// mol_vecs[m] = mean over 25 atoms of hidden -> f32 out
__global__ __launch_bounds__(256) void k_molmean(const float* __restrict__ hidden,
                                                 float* __restrict__ out) {
    const int m = blockIdx.x, c = threadIdx.x;
    float s = 0.f;
#pragma unroll
    for (int a = 0; a < APM; ++a)
        s += hidden[((long)m * APM + a) * H + c];
    out[(long)m * H + c] = s * (1.f / APM);
}

extern "C" void kernel_launch(void* const* d_in, const int* in_sizes, int n_in,
                              void* d_out, int out_size, void* d_ws, size_t ws_size,
                              hipStream_t stream) {
    (void)in_sizes; (void)n_in; (void)out_size;
    const float* fatoms  = (const float*)d_in[0];
    const float* fbonds  = (const float*)d_in[1];
    const float* tree_in = (const float*)d_in[2];
    const int* agraph    = (const int*)d_in[3];
    const int* bgraph    = (const int*)d_in[4];
    const int* pair_idx  = (const int*)d_in[5];
    const float* W_i = (const float*)d_in[6];
    const float* W_h = (const float*)d_in[7];
    const float* W_o = (const float*)d_in[8];
    const float* b_o = (const float*)d_in[9];

    float* out = (float*)d_out;   // [mol_vecs 2000*256 | collated 10000*256], f32

    const size_t WFRAG = 10 * 16 * 64 * 8;   // u16 elems per frag table
    const size_t need = ((size_t)NMESS + 2 * (size_t)NBND) * H * sizeof(u16)
                        + 2 * WFRAG * sizeof(u16);
    if (ws_size < need) return;   // diagnostic guard

    u16* tree    = (u16*)d_ws;
    u16* gmA     = tree + (size_t)NMESS * H;
    u16* gmB     = gmA + (size_t)NBND * H;
    u16* wfrag_h = gmB + (size_t)NBND * H;
    u16* wfrag_o = wfrag_h + WFRAG;
    float* hidden = (float*)gmA;   // gmA dead after mp#3

    const int GB = (NBND + 63) / 64;   // 1563
    const int GA = (NATM + 63) / 64;   // 782

    k_treecvt<<<(NMESS * H) / 1024, 256, 0, stream>>>(tree_in, tree);
    k_wfrag<<<160, 64, 0, stream>>>(W_h, 256, 0, W_i, BF, BF, wfrag_h);
    k_wfrag<<<160, 64, 0, stream>>>(W_o, 291, AF, W_o, 291, AF, wfrag_o);

    k_main<0><<<GB, 256, 0, stream>>>(nullptr, tree, gmA, fbonds, wfrag_h, nullptr, gmA, nullptr);
    k_main<1><<<GB, 256, 0, stream>>>(bgraph, tree, gmA, fbonds, wfrag_h, nullptr, gmB, nullptr);
    k_main<1><<<GB, 256, 0, stream>>>(bgraph, tree, gmB, fbonds, wfrag_h, nullptr, gmA, nullptr);
    k_main<1><<<GB, 256, 0, stream>>>(bgraph, tree, gmA, fbonds, wfrag_h, nullptr, gmB, nullptr);
    k_collated<<<NPAIR / 4, 256, 0, stream>>>(pair_idx, gmB, out + (size_t)NMOL * H);
    k_main<2><<<GA, 256, 0, stream>>>(agraph, tree, gmB, fatoms, wfrag_o, b_o, nullptr, hidden);
    k_molmean<<<NMOL, 256, 0, stream>>>(hidden, out);
}